// Round 1
// baseline (707.296 us; speedup 1.0000x reference)
//
#include <hip/hip_runtime.h>
#include <math.h>

// Problem constants (match reference)
#define BB 32
#define TT 2048
#define FF 2048
#define DQ 1024
#define UNITS 1024
#define HALF 1024          // F/2
#define CDIM 2048          // HALF + DQ
#define TC 32              // rows per chunk in streaming kernel
#define NC (TT / TC)       // 64 chunks per batch

// Workspace layout (floats):
//   [0, 2048)              w = W1 @ V              (2048)
//   [2048]                 c0 = b1.V + bV          (1)
//   [2064, 2096)           qb[b]                   (32)
//   [4096, 69632)          raw scores              (B*T = 65536)
//   [69632, 71680)         m_c per chunk           (B*NC = 2048)
//   [71680, 73728)         l_c per chunk           (2048)
//   [73728, 73728+4194304) ctx partials            (B*NC*F = 16 MiB)
// Total ~16.3 MiB.

// ---------------------------------------------------------------------------
// Kernel 0a: w[c] = sum_u W1[c,u] * V[u];  task 2048 computes c0 = b1.V + bV
// One wave per task.
__global__ void compute_w_kernel(const float* __restrict__ W1,
                                 const float* __restrict__ b1,
                                 const float* __restrict__ V,
                                 const float* __restrict__ bV,
                                 float* __restrict__ ws_w,
                                 float* __restrict__ ws_c0) {
    int g = blockIdx.x * 4 + (threadIdx.x >> 6);
    int lane = threadIdx.x & 63;
    if (g > CDIM) return;
    const float* src = (g < CDIM) ? (W1 + (size_t)g * UNITS) : b1;
    float acc = 0.f;
#pragma unroll
    for (int k = 0; k < UNITS / 256; ++k) {    // 4 iters, 64 lanes * 4 floats
        int idx = k * 256 + lane * 4;
        float4 a = *(const float4*)(src + idx);
        float4 v = *(const float4*)(V + idx);
        acc += a.x * v.x + a.y * v.y + a.z * v.z + a.w * v.w;
    }
#pragma unroll
    for (int off = 32; off >= 1; off >>= 1) acc += __shfl_down(acc, off, 64);
    if (lane == 0) {
        if (g < CDIM) ws_w[g] = acc;
        else          *ws_c0 = acc + bV[0];
    }
}

// ---------------------------------------------------------------------------
// Kernel 0b: qb[b] = query[b,:] . w[1024:2048] + c0.  One wave per b.
__global__ void compute_qb_kernel(const float* __restrict__ query,
                                  const float* __restrict__ ws_w,
                                  const float* __restrict__ ws_c0,
                                  float* __restrict__ ws_qb) {
    int g = blockIdx.x * 4 + (threadIdx.x >> 6);
    int lane = threadIdx.x & 63;
    if (g >= BB) return;
    const float* q = query + (size_t)g * DQ;
    const float* wq = ws_w + HALF;
    float acc = 0.f;
#pragma unroll
    for (int k = 0; k < DQ / 256; ++k) {
        int idx = k * 256 + lane * 4;
        float4 a = *(const float4*)(q + idx);
        float4 w = *(const float4*)(wq + idx);
        acc += a.x * w.x + a.y * w.y + a.z * w.z + a.w * w.w;
    }
#pragma unroll
    for (int off = 32; off >= 1; off >>= 1) acc += __shfl_down(acc, off, 64);
    if (lane == 0) ws_qb[g] = acc + *ws_c0;
}

// ---------------------------------------------------------------------------
// Kernel A: single-pass stream over values. Each block handles one (b, chunk)
// of TC rows. Per row-pair: read row once into registers (thread tid owns
// f = tid*4..+3 and f = 1024+tid*4..+3), compute key-half dot partial,
// block-reduce -> score, then online-softmax update of register-resident
// context accumulators from the SAME registers (values read exactly once).
__global__ void attn_stream_kernel(const float* __restrict__ values,
                                   const float* __restrict__ ws_w,
                                   const float* __restrict__ ws_qb,
                                   float* __restrict__ ws_scores,
                                   float* __restrict__ ws_m,
                                   float* __restrict__ ws_l,
                                   float* __restrict__ ws_ctx) {
    const int blk = blockIdx.x;           // 0 .. B*NC-1
    const int b = blk / NC;
    const int chunk = blk % NC;
    const int t0 = chunk * TC;
    const int tid = threadIdx.x;
    const int lane = tid & 63;
    const int wv = tid >> 6;

    __shared__ float red[16];             // [parity(2)][wave(4)][row-in-pair(2)]

    const float4 w4 = *(const float4*)(ws_w + tid * 4);
    const float qb = ws_qb[b];

    const float* vbase = values + (size_t)b * TT * FF;

    float m = -1e30f, l = 0.f;
    float4 c0 = make_float4(0.f, 0.f, 0.f, 0.f);
    float4 c1 = make_float4(0.f, 0.f, 0.f, 0.f);

    for (int r = 0; r < TC; r += 2) {
        const float* row0 = vbase + (size_t)(t0 + r) * FF;
        const float* row1 = row0 + FF;
        float4 a0 = *(const float4*)(row0 + tid * 4);
        float4 a1 = *(const float4*)(row0 + HALF + tid * 4);
        float4 e0 = *(const float4*)(row1 + tid * 4);
        float4 e1 = *(const float4*)(row1 + HALF + tid * 4);

        float pa = a0.x * w4.x + a0.y * w4.y + a0.z * w4.z + a0.w * w4.w;
        float pb = e0.x * w4.x + e0.y * w4.y + e0.z * w4.z + e0.w * w4.w;
#pragma unroll
        for (int off = 32; off >= 1; off >>= 1) {
            pa += __shfl_down(pa, off, 64);
            pb += __shfl_down(pb, off, 64);
        }
        const int par = (r >> 1) & 1;
        if (lane == 0) {
            red[par * 8 + wv * 2 + 0] = pa;
            red[par * 8 + wv * 2 + 1] = pb;
        }
        __syncthreads();
        float sa = red[par * 8 + 0] + red[par * 8 + 2] + red[par * 8 + 4] + red[par * 8 + 6] + qb;
        float sb = red[par * 8 + 1] + red[par * 8 + 3] + red[par * 8 + 5] + red[par * 8 + 7] + qb;
        if (tid == 0) {
            ws_scores[b * TT + t0 + r]     = sa;
            ws_scores[b * TT + t0 + r + 1] = sb;
        }
        // online softmax update: row a
        {
            float mn = fmaxf(m, sa);
            float scl = __expf(m - mn);
            float p = __expf(sa - mn);
            l = l * scl + p;
            c0.x = c0.x * scl + p * a0.x; c0.y = c0.y * scl + p * a0.y;
            c0.z = c0.z * scl + p * a0.z; c0.w = c0.w * scl + p * a0.w;
            c1.x = c1.x * scl + p * a1.x; c1.y = c1.y * scl + p * a1.y;
            c1.z = c1.z * scl + p * a1.z; c1.w = c1.w * scl + p * a1.w;
            m = mn;
        }
        // row b
        {
            float mn = fmaxf(m, sb);
            float scl = __expf(m - mn);
            float p = __expf(sb - mn);
            l = l * scl + p;
            c0.x = c0.x * scl + p * e0.x; c0.y = c0.y * scl + p * e0.y;
            c0.z = c0.z * scl + p * e0.z; c0.w = c0.w * scl + p * e0.w;
            c1.x = c1.x * scl + p * e1.x; c1.y = c1.y * scl + p * e1.y;
            c1.z = c1.z * scl + p * e1.z; c1.w = c1.w * scl + p * e1.w;
            m = mn;
        }
    }

    if (tid == 0) { ws_m[blk] = m; ws_l[blk] = l; }
    float* cdst = ws_ctx + (size_t)blk * FF;
    *(float4*)(cdst + tid * 4) = c0;
    *(float4*)(cdst + HALF + tid * 4) = c1;
}

// ---------------------------------------------------------------------------
// Kernel B: per (b, seg) combine chunk partials, write attn weights + context.
// grid = B*8 blocks, 256 threads; seg covers 256 t-values and 256 f-columns.
__global__ void combine_kernel(const float* __restrict__ ws_scores,
                               const float* __restrict__ ws_m,
                               const float* __restrict__ ws_l,
                               const float* __restrict__ ws_ctx,
                               float* __restrict__ out) {
    const int b = blockIdx.x >> 3;
    const int seg = blockIdx.x & 7;
    const int tid = threadIdx.x;

    __shared__ float ms[NC], ls[NC];
    for (int c = tid; c < NC; c += 256) {
        ms[c] = ws_m[b * NC + c];
        ls[c] = ws_l[b * NC + c];
    }
    __syncthreads();

    float mg = -1e30f;
#pragma unroll 8
    for (int c = 0; c < NC; ++c) mg = fmaxf(mg, ms[c]);
    float lg = 0.f;
#pragma unroll 8
    for (int c = 0; c < NC; ++c) lg += ls[c] * __expf(ms[c] - mg);
    const float inv = 1.0f / lg;

    // attention weights: out[B*F + b*T + t], shape (B,T,1)
    const int t = seg * 256 + tid;
    float s = ws_scores[b * TT + t];
    out[BB * FF + b * TT + t] = __expf(s - mg) * inv;

    // context: out[b*F + f], shape (B,1,F)
    const int f = seg * 256 + tid;
    float acc = 0.f;
#pragma unroll 8
    for (int c = 0; c < NC; ++c) {
        acc += ws_ctx[(size_t)(b * NC + c) * FF + f] * __expf(ms[c] - mg);
    }
    out[b * FF + f] = acc * inv;
}

// ---------------------------------------------------------------------------
extern "C" void kernel_launch(void* const* d_in, const int* in_sizes, int n_in,
                              void* d_out, int out_size, void* d_ws, size_t ws_size,
                              hipStream_t stream) {
    const float* query  = (const float*)d_in[0];   // (32, 1024)
    const float* values = (const float*)d_in[1];   // (32, 2048, 2048)
    const float* W1     = (const float*)d_in[2];   // (2048, 1024)
    const float* b1     = (const float*)d_in[3];   // (1024,)
    const float* V      = (const float*)d_in[4];   // (1024, 1)
    const float* bV     = (const float*)d_in[5];   // (1,)
    float* out = (float*)d_out;                    // 65536 ctx + 65536 attn

    float* ws        = (float*)d_ws;
    float* ws_w      = ws;            // 2048
    float* ws_c0     = ws + 2048;     // 1
    float* ws_qb     = ws + 2064;     // 32
    float* ws_scores = ws + 4096;     // 65536
    float* ws_m      = ws + 69632;    // 2048
    float* ws_l      = ws + 71680;    // 2048
    float* ws_ctx    = ws + 73728;    // 4194304

    // 0a: w = W1 @ V, c0 = b1.V + bV  (2049 wave-tasks)
    compute_w_kernel<<<513, 256, 0, stream>>>(W1, b1, V, bV, ws_w, ws_c0);
    // 0b: qb[b] = query[b] . w[1024:] + c0  (32 wave-tasks)
    compute_qb_kernel<<<8, 256, 0, stream>>>(query, ws_w, ws_c0, ws_qb);
    // A: single-pass stream over values with online softmax
    attn_stream_kernel<<<BB * NC, 256, 0, stream>>>(values, ws_w, ws_qb,
                                                    ws_scores, ws_m, ws_l, ws_ctx);
    // B: combine chunk partials, write outputs
    combine_kernel<<<BB * 8, 256, 0, stream>>>(ws_scores, ws_m, ws_l, ws_ctx, out);
}